// Round 1
// 1884.943 us; speedup vs baseline: 1.3407x; 1.3407x over previous
//
#include <hip/hip_runtime.h>

#define N_ATOMS 131072
#define M_NBR 12
#define ORIG_F 92
#define AF 64
#define NCONV 3
#define N0_CRYS 1024
#define FIN 169
#define C2 128
#define KPAD 192
#define BN_EPS 1e-5f
#define RB_TOTAL (N_ATOMS * M_NBR / 64)   // 24576 row-blocks of 64

typedef _Float16 f16;
typedef _Float16 half8 __attribute__((ext_vector_type(8)));
typedef float f32x4 __attribute__((ext_vector_type(4)));

union H8 { half8 h; ushort4 u[2]; };

__device__ __forceinline__ float sigmoidf_(float t) {
    return 1.0f / (1.0f + __expf(-t));
}
__device__ __forceinline__ float softplusf_(float t) {
    return fmaxf(t, 0.0f) + __logf(1.0f + __expf(-fabsf(t)));
}

// ---------------- embed: x = atom_fea @ W_embed + b  (writes fp32 + f16) -----
__global__ __launch_bounds__(256) void k_embed(const float* __restrict__ af,
                                               const float* __restrict__ W,
                                               const float* __restrict__ b,
                                               float* __restrict__ x,
                                               f16* __restrict__ xh) {
    int i = blockIdx.x * 256 + threadIdx.x;   // i < N*64
    int n = i >> 6, f = i & 63;
    float acc = b[f];
    for (int k = 0; k < ORIG_F; ++k)
        acc = fmaf(af[(size_t)n * ORIG_F + k], W[k * AF + f], acc);
    x[i] = acc;
    xh[i] = (f16)acc;
}

// ---------------- cvt nbr_fea -> f16 padded [N*M][44] ----------------
__global__ __launch_bounds__(256) void k_cvt_nbrf(const float* __restrict__ nf,
                                                  f16* __restrict__ nfh) {
    const int r0 = blockIdx.x * 16;
    for (int i = threadIdx.x; i < 16 * 44; i += 256) {
        int r = i / 44, k = i - r * 44;
        size_t row = (size_t)(r0 + r);
        nfh[row * 44 + k] = (k < 41) ? (f16)nf[row * 41 + k] : (f16)0.0f;
    }
}

// ---------------- prep W^T: Wt[c][k] f16, k padded to 192 ----------------
__global__ __launch_bounds__(256) void k_prepW(const float* __restrict__ W,
                                               f16* __restrict__ Wt) {
    int i = blockIdx.x * 256 + threadIdx.x;    // i < 128*192
    if (i >= C2 * KPAD) return;
    int c = i / KPAD, k = i - c * KPAD;
    Wt[i] = (k < FIN) ? (f16)W[k * C2 + c] : (f16)0.0f;
}

// ---------------- MFMA gemm: gated = concat-rows @ W + b  (+ fused BN1 stats)
// block = 256 (4 waves). Block tile: 64 rows x 128 cols.
// Wave (w>>1 = row-half, w&1 = col-half): 32 rows x 64 cols = 2x4 MFMA frags.
// NO LDS STAGING: each lane loads its A-fragments directly from global.
// Per kc-chunk the source is uniform: kc0/1 = self row (xh), kc2/3 = gathered
// neighbor row (xh, L2/L3-resident: xh is 16 MB), kc4/5 = nbr_fea (stride 44,
// 8B-aligned chunks). This removes all in-loop barriers -> loads pipeline
// across rb-iterations instead of serializing behind __syncthreads.
__global__ __launch_bounds__(256) void k_gemmh(const f16* __restrict__ xh,
                                               const f16* __restrict__ nfh,
                                               const int* __restrict__ nidx,
                                               const f16* __restrict__ Wt,
                                               const float* __restrict__ bl,
                                               f16* __restrict__ gated,
                                               float* __restrict__ stats) {
    __shared__ float redS[128], redQ[128];

    const int tid = threadIdx.x;
    const int wv = tid >> 6;
    const int lane = tid & 63;
    const int quad = lane >> 4;
    const int l16 = lane & 15;
    const int rhalf = wv >> 1;
    const int c0w = (wv & 1) * 64;

    if (tid < 128) { redS[tid] = 0.0f; redQ[tid] = 0.0f; }

    half8 Bf[6][4];
    float bias_[4];
    float ssum[4] = {0, 0, 0, 0}, ssq[4] = {0, 0, 0, 0};
#pragma unroll
    for (int ct = 0; ct < 4; ++ct) {
        int c = c0w + ct * 16 + l16;
        bias_[ct] = bl[c];
#pragma unroll
        for (int kc = 0; kc < 6; ++kc)
            Bf[kc][ct] = *(const half8*)&Wt[c * KPAD + kc * 32 + quad * 8];
    }

    const ushort4 z4 = make_ushort4(0, 0, 0, 0);

    for (int rb = blockIdx.x; rb < RB_TOTAL; rb += gridDim.x) {
        const int row0 = rb * 64 + rhalf * 32 + l16;
        const int row1 = row0 + 16;
        const int n0s = (int)((unsigned)row0 / 12u);
        const int n1s = (int)((unsigned)row1 / 12u);
        const int n0g = nidx[row0];
        const int n1g = nidx[row1];

        H8 a0[6], a1[6];
        {
            const f16* xs = xh + (size_t)n0s * 64;
            const f16* xg = xh + (size_t)n0g * 64;
            const f16* nf = nfh + (size_t)row0 * 44;
            a0[0].h = *(const half8*)&xs[quad * 8];
            a0[1].h = *(const half8*)&xs[32 + quad * 8];
            a0[2].h = *(const half8*)&xg[quad * 8];
            a0[3].h = *(const half8*)&xg[32 + quad * 8];
            a0[4].u[0] = *(const ushort4*)&nf[quad * 8];          // byte off row*88+quad*16: 8B aligned
            a0[4].u[1] = *(const ushort4*)&nf[quad * 8 + 4];
            a0[5].u[0] = z4; a0[5].u[1] = z4;
            if (quad == 0) {
                a0[5].u[0] = *(const ushort4*)&nf[32];            // cols 160..167
                a0[5].u[1] = *(const ushort4*)&nf[36];
            } else if (quad == 1) {
                a0[5].u[0] = *(const ushort4*)&nf[40];            // cols 168..171 (+pad zeros 41..43)
            }                                                     // cols 172..191 stay zero
        }
        {
            const f16* xs = xh + (size_t)n1s * 64;
            const f16* xg = xh + (size_t)n1g * 64;
            const f16* nf = nfh + (size_t)row1 * 44;
            a1[0].h = *(const half8*)&xs[quad * 8];
            a1[1].h = *(const half8*)&xs[32 + quad * 8];
            a1[2].h = *(const half8*)&xg[quad * 8];
            a1[3].h = *(const half8*)&xg[32 + quad * 8];
            a1[4].u[0] = *(const ushort4*)&nf[quad * 8];
            a1[4].u[1] = *(const ushort4*)&nf[quad * 8 + 4];
            a1[5].u[0] = z4; a1[5].u[1] = z4;
            if (quad == 0) {
                a1[5].u[0] = *(const ushort4*)&nf[32];
                a1[5].u[1] = *(const ushort4*)&nf[36];
            } else if (quad == 1) {
                a1[5].u[0] = *(const ushort4*)&nf[40];
            }
        }

        f32x4 acc[2][4];
#pragma unroll
        for (int rf = 0; rf < 2; ++rf)
#pragma unroll
            for (int ct = 0; ct < 4; ++ct) acc[rf][ct] = (f32x4){0, 0, 0, 0};

#pragma unroll
        for (int kc = 0; kc < 6; ++kc) {
#pragma unroll
            for (int ct = 0; ct < 4; ++ct) {
                acc[0][ct] = __builtin_amdgcn_mfma_f32_16x16x32_f16(a0[kc].h, Bf[kc][ct], acc[0][ct], 0, 0, 0);
                acc[1][ct] = __builtin_amdgcn_mfma_f32_16x16x32_f16(a1[kc].h, Bf[kc][ct], acc[1][ct], 0, 0, 0);
            }
        }

        // epilogue: C layout col=lane&15, row=quad*4+e
#pragma unroll
        for (int rf = 0; rf < 2; ++rf) {
            int rbase = rb * 64 + rhalf * 32 + rf * 16 + quad * 4;
#pragma unroll
            for (int ct = 0; ct < 4; ++ct) {
                int c = c0w + ct * 16 + l16;
#pragma unroll
                for (int e = 0; e < 4; ++e) {
                    float v = acc[rf][ct][e] + bias_[ct];
                    gated[(size_t)(rbase + e) * 128 + c] = (f16)v;
                    ssum[ct] += v;
                    ssq[ct] = fmaf(v, v, ssq[ct]);
                }
            }
        }
    }

    // BN1 stats: quad-reduce, LDS-reduce, one global atomic per channel per block
    __syncthreads();   // makes redS/redQ zero-init visible (no barriers in main loop)
#pragma unroll
    for (int ct = 0; ct < 4; ++ct) {
        float s = ssum[ct], q = ssq[ct];
        s += __shfl_xor(s, 16); s += __shfl_xor(s, 32);
        q += __shfl_xor(q, 16); q += __shfl_xor(q, 32);
        if (quad == 0) {
            atomicAdd(&redS[c0w + ct * 16 + l16], s);
            atomicAdd(&redQ[c0w + ct * 16 + l16], q);
        }
    }
    __syncthreads();
    if (tid < 128) {
        atomicAdd(&stats[tid], redS[tid]);
        atomicAdd(&stats[128 + tid], redQ[tid]);
    }
}

// ---------------- convB: BN1 + sigmoid*softplus + sum over M (+ BN2 stats) ----
// 8 lanes per atom, 8 channels per lane -> half8 (16B/lane) gated loads,
// float4 ns stores. BN2 stats reduced via shfl_xor(8/16/32) within octet group.
__global__ __launch_bounds__(256) void k_convB(const f16* __restrict__ gated,
                                               const float* __restrict__ g1,
                                               const float* __restrict__ be1,
                                               float* __restrict__ stats,
                                               float* __restrict__ ns) {
    const int tid = threadIdx.x;
    const int s8 = tid & 7;            // channel octet: channels s8*8 .. s8*8+7
    const int arow = tid >> 3;         // 0..31: atom slot within block
    const int f0 = s8 * 8;
    const float cnt1 = (float)N_ATOMS * M_NBR;

    float A1[8], B1[8], A2[8], B2[8];
#pragma unroll
    for (int j = 0; j < 8; ++j) {
        int f = f0 + j;
        float m1 = stats[f] / cnt1;
        float v1 = stats[128 + f] / cnt1 - m1 * m1;
        float m2 = stats[64 + f] / cnt1;
        float v2 = stats[192 + f] / cnt1 - m2 * m2;
        float i1 = rsqrtf(v1 + BN_EPS);
        float i2 = rsqrtf(v2 + BN_EPS);
        A1[j] = g1[f] * i1;       B1[j] = be1[f] - A1[j] * m1;
        A2[j] = g1[64 + f] * i2;  B2[j] = be1[64 + f] - A2[j] * m2;
    }

    float lsum[8] = {0, 0, 0, 0, 0, 0, 0, 0};
    float lsq[8]  = {0, 0, 0, 0, 0, 0, 0, 0};
    for (int n = blockIdx.x * 32 + arow; n < N_ATOMS; n += gridDim.x * 32) {
        const f16* gp = gated + (size_t)n * (M_NBR * C2);
        float acc[8] = {0, 0, 0, 0, 0, 0, 0, 0};
#pragma unroll
        for (int m = 0; m < M_NBR; ++m) {
            half8 ga = *(const half8*)&gp[m * 128 + f0];
            half8 gb = *(const half8*)&gp[m * 128 + 64 + f0];
#pragma unroll
            for (int j = 0; j < 8; ++j) {
                float flt = sigmoidf_(fmaf(A1[j], (float)ga[j], B1[j]));
                float cor = softplusf_(fmaf(A2[j], (float)gb[j], B2[j]));
                acc[j] = fmaf(flt, cor, acc[j]);
            }
        }
        f32x4 o0 = {acc[0], acc[1], acc[2], acc[3]};
        f32x4 o1 = {acc[4], acc[5], acc[6], acc[7]};
        *(f32x4*)&ns[(size_t)n * 64 + f0] = o0;
        *(f32x4*)&ns[(size_t)n * 64 + f0 + 4] = o1;
#pragma unroll
        for (int j = 0; j < 8; ++j) {
            lsum[j] += acc[j];
            lsq[j] = fmaf(acc[j], acc[j], lsq[j]);
        }
    }

    // lanes sharing s8 differ in lane-id bits 3,4,5
#pragma unroll
    for (int j = 0; j < 8; ++j) {
        float s = lsum[j], q = lsq[j];
        s += __shfl_xor(s, 8);  q += __shfl_xor(q, 8);
        s += __shfl_xor(s, 16); q += __shfl_xor(q, 16);
        s += __shfl_xor(s, 32); q += __shfl_xor(q, 32);
        lsum[j] = s; lsq[j] = q;
    }
    __shared__ float rs[64], rq[64];
    if (tid < 64) { rs[tid] = 0.0f; rq[tid] = 0.0f; }
    __syncthreads();
    if ((tid & 63) < 8) {   // lanes 0..7 of each wave hold their octet's totals
#pragma unroll
        for (int j = 0; j < 8; ++j) {
            atomicAdd(&rs[f0 + j], lsum[j]);
            atomicAdd(&rq[f0 + j], lsq[j]);
        }
    }
    __syncthreads();
    if (tid < 64) {
        atomicAdd(&stats[256 + tid], rs[tid]);
        atomicAdd(&stats[320 + tid], rq[tid]);
    }
}

// ---------------- convC: x = softplus(x + BN2(ns))  (writes fp32 + f16) ------
__global__ __launch_bounds__(256) void k_convC(float* __restrict__ x,
                                               f16* __restrict__ xh,
                                               const float* __restrict__ ns,
                                               const float* __restrict__ g2,
                                               const float* __restrict__ be2,
                                               const float* __restrict__ stats) {
    const int i = blockIdx.x * 256 + threadIdx.x;
    const int f = i & 63;
    const float cnt = (float)N_ATOMS;
    float m = stats[256 + f] / cnt;
    float v = stats[320 + f] / cnt - m * m;
    float inv = rsqrtf(v + BN_EPS);
    float A = g2[f] * inv, B = be2[f] - A * m;
    float t = x[i] + fmaf(A, ns[i], B);
    float o = softplusf_(t);
    x[i] = o;
    xh[i] = (f16)o;
}

// ---------------- pool: per-crystal mean (sorted idx, binary search) ---------
__global__ __launch_bounds__(64) void k_pool(const float* __restrict__ x,
                                             const int* __restrict__ cidx,
                                             float* __restrict__ crys) {
    const int s = blockIdx.x;
    const int f = threadIdx.x;
    int lo = 0, hi = N_ATOMS;
    while (lo < hi) { int mid = (lo + hi) >> 1; if (cidx[mid] < s) lo = mid + 1; else hi = mid; }
    int lo2 = lo, hi2 = N_ATOMS;
    while (lo2 < hi2) { int mid = (lo2 + hi2) >> 1; if (cidx[mid] < s + 1) lo2 = mid + 1; else hi2 = mid; }
    float sum = 0.0f;
    for (int i = lo; i < lo2; ++i) sum += x[(size_t)i * 64 + f];
    float cnt = fmaxf((float)(lo2 - lo), 1.0f);
    crys[s * 64 + f] = sum / cnt;
}

// ---------------- head ----------------
__global__ __launch_bounds__(128) void k_head(const float* __restrict__ crys,
                                              const float* __restrict__ W1,
                                              const float* __restrict__ b1,
                                              const float* __restrict__ W2,
                                              const float* __restrict__ b2,
                                              float* __restrict__ out) {
    __shared__ float a_sh[64];
    __shared__ float r_sh[128];
    const int n = blockIdx.x;
    const int tid = threadIdx.x;
    if (tid < 64) a_sh[tid] = softplusf_(crys[n * 64 + tid]);
    __syncthreads();
    for (int p = 0; p < 2; ++p) {
        float acc = b1[p * 128 + tid];
#pragma unroll
        for (int f2 = 0; f2 < 64; ++f2)
            acc = fmaf(a_sh[f2], W1[(p * 64 + f2) * 128 + tid], acc);
        float contrib = softplusf_(acc) * W2[p * 128 + tid];
        r_sh[tid] = contrib;
        __syncthreads();
        for (int sft = 64; sft > 0; sft >>= 1) {
            if (tid < sft) r_sh[tid] += r_sh[tid + sft];
            __syncthreads();
        }
        if (tid == 0) out[n * 2 + p] = r_sh[0] + b2[p];
        __syncthreads();
    }
}

extern "C" void kernel_launch(void* const* d_in, const int* in_sizes, int n_in,
                              void* d_out, int out_size, void* d_ws, size_t ws_size,
                              hipStream_t stream) {
    const float* atom_fea = (const float*)d_in[0];
    const float* nbr_fea  = (const float*)d_in[1];
    const float* W_embed  = (const float*)d_in[2];
    const float* b_embed  = (const float*)d_in[3];
    const float* conv_W   = (const float*)d_in[4];
    const float* conv_b   = (const float*)d_in[5];
    const float* conv_g1  = (const float*)d_in[6];
    const float* conv_be1 = (const float*)d_in[7];
    const float* conv_g2  = (const float*)d_in[8];
    const float* conv_be2 = (const float*)d_in[9];
    const float* head_W1  = (const float*)d_in[10];
    const float* head_b1  = (const float*)d_in[11];
    const float* head_W2  = (const float*)d_in[12];
    const float* head_b2  = (const float*)d_in[13];
    const int*   nidx     = (const int*)d_in[14];
    const int*   cryst    = (const int*)d_in[15];

    // workspace layout (unchanged)
    char* w = (char*)d_ws;
    float* x      = (float*)w;                        //  33,554,432
    f16*   xh     = (f16*)(w + 33554432);             //  16,777,216
    f16*   gated  = (f16*)(w + 50331648);             // 402,653,184
    float* ns     = (float*)(w + 452984832);          //  33,554,432
    f16*   nfh    = (f16*)(w + 486539264);            // 138,412,032
    f16*   Wt     = (f16*)(w + 624951296);            //      49,152
    float* stats  = (float*)(w + 625000448);          //       4,608
    const size_t required = 625000448ull + 4608ull;
    if (ws_size < required) {
        hipMemsetAsync(d_out, 0x7F, 4, stream);
        return;
    }

    hipMemsetAsync(stats, 0, NCONV * 384 * sizeof(float), stream);

    k_cvt_nbrf<<<N_ATOMS * M_NBR / 16, 256, 0, stream>>>(nbr_fea, nfh);
    k_embed<<<N_ATOMS * AF / 256, 256, 0, stream>>>(atom_fea, W_embed, b_embed, x, xh);

    for (int l = 0; l < NCONV; ++l) {
        float* st = stats + l * 384;
        k_prepW<<<(C2 * KPAD + 255) / 256, 256, 0, stream>>>(conv_W + (size_t)l * FIN * C2, Wt);
        k_gemmh<<<2048, 256, 0, stream>>>(xh, nfh, nidx, Wt, conv_b + l * C2, gated, st);
        k_convB<<<2048, 256, 0, stream>>>(gated, conv_g1 + l * C2, conv_be1 + l * C2, st, ns);
        k_convC<<<N_ATOMS * AF / 256, 256, 0, stream>>>(x, xh, ns, conv_g2 + l * AF, conv_be2 + l * AF, st);
    }

    float* crys = (float*)d_out + N0_CRYS * 2;   // crys_fea follows out
    k_pool<<<N0_CRYS, 64, 0, stream>>>(x, cryst, crys);
    k_head<<<N0_CRYS, 128, 0, stream>>>(crys, head_W1, head_b1, head_W2, head_b2, (float*)d_out);
}

// Round 2
// 1746.370 us; speedup vs baseline: 1.4470x; 1.0793x over previous
//
#include <hip/hip_runtime.h>

#define N_ATOMS 131072
#define M_NBR 12
#define ORIG_F 92
#define AF 64
#define NCONV 3
#define N0_CRYS 1024
#define FIN 169
#define C2 128
#define KPAD 192
#define BN_EPS 1e-5f
#define RB_TOTAL (N_ATOMS * M_NBR / 64)   // 24576 row-blocks of 64 (gemmA)
#define BT_TOTAL (N_ATOMS * M_NBR / 96)   // 16384 row-blocks of 96 (gemmB)

typedef _Float16 f16;
typedef _Float16 half8 __attribute__((ext_vector_type(8)));
typedef float f32x4 __attribute__((ext_vector_type(4)));

union H8 { half8 h; ushort4 u[2]; };

__device__ __forceinline__ float sigmoidf_(float t) {
    return 1.0f / (1.0f + __expf(-t));
}
__device__ __forceinline__ float softplusf_(float t) {
    return fmaxf(t, 0.0f) + __logf(1.0f + __expf(-fabsf(t)));
}

// ---------------- embed: x = atom_fea @ W_embed + b  (writes fp32 + f16) -----
__global__ __launch_bounds__(256) void k_embed(const float* __restrict__ af,
                                               const float* __restrict__ W,
                                               const float* __restrict__ b,
                                               float* __restrict__ x,
                                               f16* __restrict__ xh) {
    int i = blockIdx.x * 256 + threadIdx.x;   // i < N*64
    int n = i >> 6, f = i & 63;
    float acc = b[f];
    for (int k = 0; k < ORIG_F; ++k)
        acc = fmaf(af[(size_t)n * ORIG_F + k], W[k * AF + f], acc);
    x[i] = acc;
    xh[i] = (f16)acc;
}

// ---------------- cvt nbr_fea -> f16 padded [N*M][44], ushort2 stores --------
__global__ __launch_bounds__(256) void k_cvt_nbrf(const float* __restrict__ nf,
                                                  f16* __restrict__ nfh) {
    const int r0 = blockIdx.x * 32;
    for (int i = threadIdx.x; i < 32 * 22; i += 256) {
        int r = i / 22, k2 = i - r * 22;
        size_t row = (size_t)(r0 + r);
        int k = k2 * 2;
        float f0 = (k < 41) ? nf[row * 41 + k] : 0.0f;
        float f1 = (k + 1 < 41) ? nf[row * 41 + k + 1] : 0.0f;
        f16 two[2] = {(f16)f0, (f16)f1};
        *(ushort2*)&nfh[row * 44 + k] = *(const ushort2*)two;
    }
}

// ---------------- prep W^T: Wt[c][k] f16, k padded to 192 ----------------
__global__ __launch_bounds__(256) void k_prepW(const float* __restrict__ W,
                                               f16* __restrict__ Wt) {
    int i = blockIdx.x * 256 + threadIdx.x;    // i < 128*192
    if (i >= C2 * KPAD) return;
    int c = i / KPAD, k = i - c * KPAD;
    Wt[i] = (k < FIN) ? (f16)W[k * C2 + c] : (f16)0.0f;
}

// ---------------- gemmA: MFMA gemm, BN1 stats ONLY (no gated store) ----------
// Same structure as the verified gemmh: 64-row tile, 4 waves (2 row-half x
// 2 col-half), direct-from-global A fragments, no in-loop barriers.
__global__ __launch_bounds__(256) void k_gemmA(const f16* __restrict__ xh,
                                               const f16* __restrict__ nfh,
                                               const int* __restrict__ nidx,
                                               const f16* __restrict__ Wt,
                                               const float* __restrict__ bl,
                                               float* __restrict__ stats) {
    __shared__ float redS[128], redQ[128];

    const int tid = threadIdx.x;
    const int wv = tid >> 6;
    const int lane = tid & 63;
    const int quad = lane >> 4;
    const int l16 = lane & 15;
    const int rhalf = wv >> 1;
    const int c0w = (wv & 1) * 64;

    if (tid < 128) { redS[tid] = 0.0f; redQ[tid] = 0.0f; }

    half8 Bf[6][4];
    float bias_[4];
    float ssum[4] = {0, 0, 0, 0}, ssq[4] = {0, 0, 0, 0};
#pragma unroll
    for (int ct = 0; ct < 4; ++ct) {
        int c = c0w + ct * 16 + l16;
        bias_[ct] = bl[c];
#pragma unroll
        for (int kc = 0; kc < 6; ++kc)
            Bf[kc][ct] = *(const half8*)&Wt[c * KPAD + kc * 32 + quad * 8];
    }

    const ushort4 z4 = make_ushort4(0, 0, 0, 0);

    for (int rb = blockIdx.x; rb < RB_TOTAL; rb += gridDim.x) {
        const int row0 = rb * 64 + rhalf * 32 + l16;
        const int row1 = row0 + 16;
        const int n0s = (int)((unsigned)row0 / 12u);
        const int n1s = (int)((unsigned)row1 / 12u);
        const int n0g = nidx[row0];
        const int n1g = nidx[row1];

        H8 a0[6], a1[6];
        {
            const f16* xs = xh + (size_t)n0s * 64;
            const f16* xg = xh + (size_t)n0g * 64;
            const f16* nf = nfh + (size_t)row0 * 44;
            a0[0].h = *(const half8*)&xs[quad * 8];
            a0[1].h = *(const half8*)&xs[32 + quad * 8];
            a0[2].h = *(const half8*)&xg[quad * 8];
            a0[3].h = *(const half8*)&xg[32 + quad * 8];
            a0[4].u[0] = *(const ushort4*)&nf[quad * 8];
            a0[4].u[1] = *(const ushort4*)&nf[quad * 8 + 4];
            a0[5].u[0] = z4; a0[5].u[1] = z4;
            if (quad == 0) {
                a0[5].u[0] = *(const ushort4*)&nf[32];
                a0[5].u[1] = *(const ushort4*)&nf[36];
            } else if (quad == 1) {
                a0[5].u[0] = *(const ushort4*)&nf[40];
            }
        }
        {
            const f16* xs = xh + (size_t)n1s * 64;
            const f16* xg = xh + (size_t)n1g * 64;
            const f16* nf = nfh + (size_t)row1 * 44;
            a1[0].h = *(const half8*)&xs[quad * 8];
            a1[1].h = *(const half8*)&xs[32 + quad * 8];
            a1[2].h = *(const half8*)&xg[quad * 8];
            a1[3].h = *(const half8*)&xg[32 + quad * 8];
            a1[4].u[0] = *(const ushort4*)&nf[quad * 8];
            a1[4].u[1] = *(const ushort4*)&nf[quad * 8 + 4];
            a1[5].u[0] = z4; a1[5].u[1] = z4;
            if (quad == 0) {
                a1[5].u[0] = *(const ushort4*)&nf[32];
                a1[5].u[1] = *(const ushort4*)&nf[36];
            } else if (quad == 1) {
                a1[5].u[0] = *(const ushort4*)&nf[40];
            }
        }

        f32x4 acc[2][4];
#pragma unroll
        for (int rf = 0; rf < 2; ++rf)
#pragma unroll
            for (int ct = 0; ct < 4; ++ct) acc[rf][ct] = (f32x4){0, 0, 0, 0};

#pragma unroll
        for (int kc = 0; kc < 6; ++kc) {
#pragma unroll
            for (int ct = 0; ct < 4; ++ct) {
                acc[0][ct] = __builtin_amdgcn_mfma_f32_16x16x32_f16(a0[kc].h, Bf[kc][ct], acc[0][ct], 0, 0, 0);
                acc[1][ct] = __builtin_amdgcn_mfma_f32_16x16x32_f16(a1[kc].h, Bf[kc][ct], acc[1][ct], 0, 0, 0);
            }
        }

        // stats-only epilogue
#pragma unroll
        for (int rf = 0; rf < 2; ++rf)
#pragma unroll
            for (int ct = 0; ct < 4; ++ct)
#pragma unroll
                for (int e = 0; e < 4; ++e) {
                    float v = acc[rf][ct][e] + bias_[ct];
                    ssum[ct] += v;
                    ssq[ct] = fmaf(v, v, ssq[ct]);
                }
    }

    __syncthreads();   // makes redS/redQ zero-init visible
#pragma unroll
    for (int ct = 0; ct < 4; ++ct) {
        float s = ssum[ct], q = ssq[ct];
        s += __shfl_xor(s, 16); s += __shfl_xor(s, 32);
        q += __shfl_xor(q, 16); q += __shfl_xor(q, 32);
        if (quad == 0) {
            atomicAdd(&redS[c0w + ct * 16 + l16], s);
            atomicAdd(&redQ[c0w + ct * 16 + l16], q);
        }
    }
    __syncthreads();
    if (tid < 128) {
        atomicAdd(&stats[tid], redS[tid]);
        atomicAdd(&stats[128 + tid], redQ[tid]);
    }
}

// ---------------- gemmB: recompute gemm + BN1 + sigmoid*softplus + atom-sum --
// Block = 256 thr (4 waves) x 96 rows (= 8 whole atoms; lcm(12,16)=48).
// Wave w: rows (w>>1)*48 .. +47 (exactly 4 atoms), columns = tiles
// {2s,2s+1,4+2s,5+2s} with s=w&1, so filter col c and core col c+64 live in
// the SAME lane (product is in-register). Per-4-row partials exchanged via
// per-wave LDS scratch to form exact per-atom sums -> ns + BN2 stats.
__global__ __launch_bounds__(256) void k_gemmB(const f16* __restrict__ xh,
                                               const f16* __restrict__ nfh,
                                               const int* __restrict__ nidx,
                                               const f16* __restrict__ Wt,
                                               const float* __restrict__ bl,
                                               const float* __restrict__ g1,
                                               const float* __restrict__ be1,
                                               float* __restrict__ stats,
                                               float* __restrict__ ns) {
    __shared__ float scr[4][12][33];   // [wave][4-row group][col] (+pad)
    __shared__ float rs[64], rq[64];

    const int tid = threadIdx.x;
    const int wv = tid >> 6;
    const int lane = tid & 63;
    const int quad = lane >> 4;
    const int l16 = lane & 15;
    const int rgrp = wv >> 1;          // row group 0/1 (48 rows each)
    const int csel = wv & 1;           // column half of the 64 product cols
    const float cnt1 = (float)N_ATOMS * M_NBR;

    if (tid < 64) { rs[tid] = 0.0f; rq[tid] = 0.0f; }
    __syncthreads();

    const int tmap[4] = {2 * csel, 2 * csel + 1, 4 + 2 * csel, 5 + 2 * csel};
    float P[4], Q[4];
    half8 Bf[4][6];
#pragma unroll
    for (int jt = 0; jt < 4; ++jt) {
        int c = tmap[jt] * 16 + l16;
        float m1 = stats[c] / cnt1;
        float v1 = stats[128 + c] / cnt1 - m1 * m1;
        float A1 = g1[c] * rsqrtf(v1 + BN_EPS);
        P[jt] = A1;
        Q[jt] = fmaf(A1, bl[c], be1[c] - A1 * m1);   // BN1 with gemm-bias folded in
#pragma unroll
        for (int kc = 0; kc < 6; ++kc)
            Bf[jt][kc] = *(const half8*)&Wt[c * KPAD + kc * 32 + quad * 8];
    }

    const ushort4 z4 = make_ushort4(0, 0, 0, 0);
    float ls[2] = {0, 0}, lq2[2] = {0, 0};

    for (int bt = blockIdx.x; bt < BT_TOTAL; bt += gridDim.x) {
        const int rw = bt * 96 + rgrp * 48;
        float part[3][2];
#pragma unroll
        for (int rt = 0; rt < 3; ++rt) {
            const int r = rw + rt * 16 + l16;
            const int nself = (int)((unsigned)r / 12u);
            const int ng = nidx[r];
            const f16* xs = xh + (size_t)nself * 64;
            const f16* xg = xh + (size_t)ng * 64;
            const f16* nf = nfh + (size_t)r * 44;
            H8 a[6];
            a[0].h = *(const half8*)&xs[quad * 8];
            a[1].h = *(const half8*)&xs[32 + quad * 8];
            a[2].h = *(const half8*)&xg[quad * 8];
            a[3].h = *(const half8*)&xg[32 + quad * 8];
            a[4].u[0] = *(const ushort4*)&nf[quad * 8];
            a[4].u[1] = *(const ushort4*)&nf[quad * 8 + 4];
            a[5].u[0] = z4; a[5].u[1] = z4;
            if (quad == 0) {
                a[5].u[0] = *(const ushort4*)&nf[32];
                a[5].u[1] = *(const ushort4*)&nf[36];
            } else if (quad == 1) {
                a[5].u[0] = *(const ushort4*)&nf[40];
            }

            f32x4 acc[4];
#pragma unroll
            for (int jt = 0; jt < 4; ++jt) acc[jt] = (f32x4){0, 0, 0, 0};
#pragma unroll
            for (int kc = 0; kc < 6; ++kc)
#pragma unroll
                for (int jt = 0; jt < 4; ++jt)
                    acc[jt] = __builtin_amdgcn_mfma_f32_16x16x32_f16(a[kc].h, Bf[jt][kc], acc[jt], 0, 0, 0);

            // C layout: row = rw + rt*16 + quad*4 + e, col = tmap[jt]*16 + l16
#pragma unroll
            for (int j = 0; j < 2; ++j) {
                float s = 0.0f;
#pragma unroll
                for (int e = 0; e < 4; ++e) {
                    float vf = fmaf(P[j],     acc[j][e],     Q[j]);       // filter col
                    float vc = fmaf(P[j + 2], acc[j + 2][e], Q[j + 2]);   // core col (+64)
                    s = fmaf(sigmoidf_(vf), softplusf_(vc), s);
                }
                part[rt][j] = s;   // sum over the 4 rows of group rt*4+quad
            }
        }
        __syncthreads();   // prev-iter scr reads done before overwrite
#pragma unroll
        for (int rt = 0; rt < 3; ++rt)
#pragma unroll
            for (int j = 0; j < 2; ++j)
                scr[wv][rt * 4 + quad][j * 16 + l16] = part[rt][j];
        __syncthreads();   // writes visible before reads
        // atom a = quad (4 atoms/wave); its 12 rows = groups 3a..3a+2
#pragma unroll
        for (int j = 0; j < 2; ++j) {
            int cj = j * 16 + l16;
            float s = scr[wv][3 * quad][cj] + scr[wv][3 * quad + 1][cj] + scr[wv][3 * quad + 2][cj];
            const int n = bt * 8 + rgrp * 4 + quad;
            ns[(size_t)n * 64 + csel * 32 + cj] = s;
            ls[j] += s;
            lq2[j] = fmaf(s, s, lq2[j]);
        }
    }

    // BN2 stats: per-lane cols are fixed (csel*32 + j*16 + l16); quads hold
    // disjoint atoms -> reduce across quads, then across waves via LDS+atomics.
#pragma unroll
    for (int j = 0; j < 2; ++j) {
        float s = ls[j], q = lq2[j];
        s += __shfl_xor(s, 16); s += __shfl_xor(s, 32);
        q += __shfl_xor(q, 16); q += __shfl_xor(q, 32);
        if (quad == 0) {
            atomicAdd(&rs[csel * 32 + j * 16 + l16], s);
            atomicAdd(&rq[csel * 32 + j * 16 + l16], q);
        }
    }
    __syncthreads();
    if (tid < 64) {
        atomicAdd(&stats[256 + tid], rs[tid]);
        atomicAdd(&stats[320 + tid], rq[tid]);
    }
}

// ---------------- convC: x = softplus(x + BN2(ns))  (writes fp32 + f16) ------
__global__ __launch_bounds__(256) void k_convC(float* __restrict__ x,
                                               f16* __restrict__ xh,
                                               const float* __restrict__ ns,
                                               const float* __restrict__ g2,
                                               const float* __restrict__ be2,
                                               const float* __restrict__ stats) {
    const int i = blockIdx.x * 256 + threadIdx.x;
    const int f = i & 63;
    const float cnt = (float)N_ATOMS;
    float m = stats[256 + f] / cnt;
    float v = stats[320 + f] / cnt - m * m;
    float inv = rsqrtf(v + BN_EPS);
    float A = g2[f] * inv, B = be2[f] - A * m;
    float t = x[i] + fmaf(A, ns[i], B);
    float o = softplusf_(t);
    x[i] = o;
    xh[i] = (f16)o;
}

// ---------------- pool: per-crystal mean (sorted idx, binary search) ---------
__global__ __launch_bounds__(64) void k_pool(const float* __restrict__ x,
                                             const int* __restrict__ cidx,
                                             float* __restrict__ crys) {
    const int s = blockIdx.x;
    const int f = threadIdx.x;
    int lo = 0, hi = N_ATOMS;
    while (lo < hi) { int mid = (lo + hi) >> 1; if (cidx[mid] < s) lo = mid + 1; else hi = mid; }
    int lo2 = lo, hi2 = N_ATOMS;
    while (lo2 < hi2) { int mid = (lo2 + hi2) >> 1; if (cidx[mid] < s + 1) lo2 = mid + 1; else hi2 = mid; }
    float sum = 0.0f;
    for (int i = lo; i < lo2; ++i) sum += x[(size_t)i * 64 + f];
    float cnt = fmaxf((float)(lo2 - lo), 1.0f);
    crys[s * 64 + f] = sum / cnt;
}

// ---------------- head ----------------
__global__ __launch_bounds__(128) void k_head(const float* __restrict__ crys,
                                              const float* __restrict__ W1,
                                              const float* __restrict__ b1,
                                              const float* __restrict__ W2,
                                              const float* __restrict__ b2,
                                              float* __restrict__ out) {
    __shared__ float a_sh[64];
    __shared__ float r_sh[128];
    const int n = blockIdx.x;
    const int tid = threadIdx.x;
    if (tid < 64) a_sh[tid] = softplusf_(crys[n * 64 + tid]);
    __syncthreads();
    for (int p = 0; p < 2; ++p) {
        float acc = b1[p * 128 + tid];
#pragma unroll
        for (int f2 = 0; f2 < 64; ++f2)
            acc = fmaf(a_sh[f2], W1[(p * 64 + f2) * 128 + tid], acc);
        float contrib = softplusf_(acc) * W2[p * 128 + tid];
        r_sh[tid] = contrib;
        __syncthreads();
        for (int sft = 64; sft > 0; sft >>= 1) {
            if (tid < sft) r_sh[tid] += r_sh[tid + sft];
            __syncthreads();
        }
        if (tid == 0) out[n * 2 + p] = r_sh[0] + b2[p];
        __syncthreads();
    }
}

extern "C" void kernel_launch(void* const* d_in, const int* in_sizes, int n_in,
                              void* d_out, int out_size, void* d_ws, size_t ws_size,
                              hipStream_t stream) {
    const float* atom_fea = (const float*)d_in[0];
    const float* nbr_fea  = (const float*)d_in[1];
    const float* W_embed  = (const float*)d_in[2];
    const float* b_embed  = (const float*)d_in[3];
    const float* conv_W   = (const float*)d_in[4];
    const float* conv_b   = (const float*)d_in[5];
    const float* conv_g1  = (const float*)d_in[6];
    const float* conv_be1 = (const float*)d_in[7];
    const float* conv_g2  = (const float*)d_in[8];
    const float* conv_be2 = (const float*)d_in[9];
    const float* head_W1  = (const float*)d_in[10];
    const float* head_b1  = (const float*)d_in[11];
    const float* head_W2  = (const float*)d_in[12];
    const float* head_b2  = (const float*)d_in[13];
    const int*   nidx     = (const int*)d_in[14];
    const int*   cryst    = (const int*)d_in[15];

    // workspace layout (gated eliminated)
    char* w = (char*)d_ws;
    float* x      = (float*)w;                        //  33,554,432
    f16*   xh     = (f16*)(w + 33554432);             //  16,777,216
    float* ns     = (float*)(w + 50331648);           //  33,554,432
    f16*   nfh    = (f16*)(w + 83886080);             // 138,412,032
    f16*   Wt     = (f16*)(w + 222298112);            //      49,152
    float* stats  = (float*)(w + 222347264);          //       4,608
    const size_t required = 222347264ull + 4608ull;
    if (ws_size < required) {
        hipMemsetAsync(d_out, 0x7F, 4, stream);
        return;
    }

    hipMemsetAsync(stats, 0, NCONV * 384 * sizeof(float), stream);

    k_cvt_nbrf<<<N_ATOMS * M_NBR / 32, 256, 0, stream>>>(nbr_fea, nfh);
    k_embed<<<N_ATOMS * AF / 256, 256, 0, stream>>>(atom_fea, W_embed, b_embed, x, xh);

    for (int l = 0; l < NCONV; ++l) {
        float* st = stats + l * 384;
        k_prepW<<<(C2 * KPAD + 255) / 256, 256, 0, stream>>>(conv_W + (size_t)l * FIN * C2, Wt);
        k_gemmA<<<2048, 256, 0, stream>>>(xh, nfh, nidx, Wt, conv_b + l * C2, st);
        k_gemmB<<<2048, 256, 0, stream>>>(xh, nfh, nidx, Wt, conv_b + l * C2,
                                          conv_g1 + l * C2, conv_be1 + l * C2, st, ns);
        k_convC<<<N_ATOMS * AF / 256, 256, 0, stream>>>(x, xh, ns, conv_g2 + l * AF, conv_be2 + l * AF, st);
    }

    float* crys = (float*)d_out + N0_CRYS * 2;   // crys_fea follows out
    k_pool<<<N0_CRYS, 64, 0, stream>>>(x, cryst, crys);
    k_head<<<N0_CRYS, 128, 0, stream>>>(crys, head_W1, head_b1, head_W2, head_b2, (float*)d_out);
}